// Round 2
// baseline (1532.516 us; speedup 1.0000x reference)
//
#include <hip/hip_runtime.h>
#include <cstdint>
#include <cstddef>

#define NN 100000
#define BN_EPS 1e-5f

static __device__ __forceinline__ float bflo(unsigned u){ return __uint_as_float(u<<16); }
static __device__ __forceinline__ float bfhi(unsigned u){ return __uint_as_float(u & 0xFFFF0000u); }
static __device__ __forceinline__ unsigned short f2bf(float f){
  unsigned u = __float_as_uint(f);
  u += 0x7FFFu + ((u>>16)&1u);   // round-to-nearest-even
  return (unsigned short)(u>>16);
}

// ---------------- graph prep ----------------

__global__ void k_hist(const int* __restrict__ dst, int* __restrict__ cnt, int E){
  int e = blockIdx.x*blockDim.x + threadIdx.x;
  if(e<E) atomicAdd(&cnt[dst[e]], 1);
}

__global__ void k_norm(const int* __restrict__ cnt, float* __restrict__ norm, int n){
  int i = blockIdx.x*blockDim.x + threadIdx.x;
  if(i<n) norm[i] = rsqrtf(fmaxf((float)cnt[i], 1.0f));
}

// single-block exclusive scan: each thread sums a contiguous chunk, block-scan of partials,
// then each thread writes its chunk's running prefix.
__global__ __launch_bounds__(1024) void k_scan(const int* __restrict__ cnt, int* __restrict__ rp, int n){
  __shared__ int sm[1024];
  int t = threadIdx.x;
  int chunk = (n + 1023)/1024;
  int lo = t*chunk, hi = min(lo+chunk, n);
  int s=0;
  for(int i=lo;i<hi;i++) s += cnt[i];
  sm[t]=s; __syncthreads();
  for(int off=1; off<1024; off<<=1){
    int v = (t>=off)? sm[t-off] : 0;
    __syncthreads();
    sm[t]+=v;
    __syncthreads();
  }
  int run = sm[t]-s;           // exclusive prefix of this chunk
  for(int i=lo;i<hi;i++){ rp[i]=run; run+=cnt[i]; }
  if(t==1023) rp[n]=sm[1023];
}

__global__ void k_scatter(const int* __restrict__ src, const int* __restrict__ dst,
                          const int* __restrict__ rp, int* __restrict__ fill,
                          int* __restrict__ esrc, int E){
  int e = blockIdx.x*blockDim.x + threadIdx.x;
  if(e<E){
    int d = dst[e];
    int pos = rp[d] + atomicAdd(&fill[d], 1);
    esrc[pos] = src[e];
  }
}

// ---------------- elementwise ----------------

__global__ void k_scale_x(const float* __restrict__ x, const float* __restrict__ norm,
                          unsigned short* __restrict__ H, int total){
  int i = blockIdx.x*blockDim.x + threadIdx.x;
  if(i<total) H[i] = f2bf(x[i] * norm[i>>7]);   // 128 feats/row
}

__global__ void k_bnrelu(const float* __restrict__ Z, const float* __restrict__ scsh,
                         const float* __restrict__ normPre, unsigned short* __restrict__ H, int total){
  int i = blockIdx.x*blockDim.x + threadIdx.x;
  if(i<total){
    int c = i & 255;
    float v = Z[i]*scsh[c] + scsh[256+c];
    v = fmaxf(v, 0.f);
    if(normPre) v *= normPre[i>>8];
    H[i] = f2bf(v);
  }
}

// ---------------- BN stats ----------------

__global__ __launch_bounds__(256) void k_colstats(const float* __restrict__ Z, float* __restrict__ sums, int M){
  int c = threadIdx.x;
  float s=0.f, s2=0.f;
  for(int r=blockIdx.x; r<M; r+=gridDim.x){
    float v = Z[(size_t)r*256 + c];
    s+=v; s2+=v*v;
  }
  atomicAdd(&sums[c], s);
  atomicAdd(&sums[256+c], s2);
}

__global__ void k_bnfin(const float* __restrict__ sums, const float* __restrict__ gamma,
                        const float* __restrict__ beta, float* __restrict__ scsh, int M){
  int c = threadIdx.x;
  float mean = sums[c]/(float)M;
  float var  = sums[256+c]/(float)M - mean*mean;
  float sc = gamma[c]*rsqrtf(var + BN_EPS);
  scsh[c] = sc;
  scsh[256+c] = beta[c] - mean*sc;
}

// ---------------- aggregation (wave per node, CSR) — bf16 out ----------------

__global__ __launch_bounds__(64) void k_agg128(const unsigned short* __restrict__ H,
    const int* __restrict__ rp, const int* __restrict__ esrc,
    const float* __restrict__ norm, unsigned short* __restrict__ out){
  int node = blockIdx.x, lane = threadIdx.x;
  int s0 = rp[node], s1 = rp[node+1];
  float a0=0.f, a1=0.f;
  int e=s0;
  for(; e+4<=s1; e+=4){
    int n0=esrc[e], n1=esrc[e+1], n2=esrc[e+2], n3=esrc[e+3];
    unsigned v0 = *(const unsigned*)(H + (size_t)n0*128 + lane*2);
    unsigned v1 = *(const unsigned*)(H + (size_t)n1*128 + lane*2);
    unsigned v2 = *(const unsigned*)(H + (size_t)n2*128 + lane*2);
    unsigned v3 = *(const unsigned*)(H + (size_t)n3*128 + lane*2);
    a0 += bflo(v0)+bflo(v1)+bflo(v2)+bflo(v3);
    a1 += bfhi(v0)+bfhi(v1)+bfhi(v2)+bfhi(v3);
  }
  for(; e<s1; e++){
    unsigned v = *(const unsigned*)(H + (size_t)esrc[e]*128 + lane*2);
    a0 += bflo(v); a1 += bfhi(v);
  }
  float nn = norm[node];
  unsigned pk = (unsigned)f2bf(a0*nn) | ((unsigned)f2bf(a1*nn) << 16);
  *(unsigned*)(out + (size_t)node*128 + lane*2) = pk;
}

__global__ __launch_bounds__(64) void k_agg256(const unsigned short* __restrict__ H,
    const int* __restrict__ rp, const int* __restrict__ esrc,
    const float* __restrict__ norm, unsigned short* __restrict__ out){
  int node = blockIdx.x, lane = threadIdx.x;
  int s0 = rp[node], s1 = rp[node+1];
  float a0=0.f,a1=0.f,a2=0.f,a3=0.f;
  int e=s0;
  for(; e+2<=s1; e+=2){
    int na=esrc[e], nb=esrc[e+1];
    uint2 va = *(const uint2*)(H + (size_t)na*256 + lane*4);
    uint2 vb = *(const uint2*)(H + (size_t)nb*256 + lane*4);
    a0 += bflo(va.x)+bflo(vb.x);
    a1 += bfhi(va.x)+bfhi(vb.x);
    a2 += bflo(va.y)+bflo(vb.y);
    a3 += bfhi(va.y)+bfhi(vb.y);
  }
  if(e<s1){
    uint2 v = *(const uint2*)(H + (size_t)esrc[e]*256 + lane*4);
    a0+=bflo(v.x); a1+=bfhi(v.x); a2+=bflo(v.y); a3+=bfhi(v.y);
  }
  float nn = norm[node];
  uint2 pk;
  pk.x = (unsigned)f2bf(a0*nn) | ((unsigned)f2bf(a1*nn) << 16);
  pk.y = (unsigned)f2bf(a2*nn) | ((unsigned)f2bf(a3*nn) << 16);
  *(uint2*)(out + (size_t)node*256 + lane*4) = pk;
}

// final aggregation over 40 features + bias + log_softmax, fused
__global__ __launch_bounds__(64) void k_agg40(const float* __restrict__ X3,
    const int* __restrict__ rp, const int* __restrict__ esrc,
    const float* __restrict__ norm, const float* __restrict__ b3,
    float* __restrict__ out){
  int node = blockIdx.x, lane = threadIdx.x;
  int s0 = rp[node], s1 = rp[node+1];
  bool act = lane < 40;
  float a = 0.f;
  int e = s0;
  for(; e+2<=s1; e+=2){
    int na=esrc[e], nb=esrc[e+1];
    float va=0.f, vb=0.f;
    if(act){ va = X3[(size_t)na*40 + lane]; vb = X3[(size_t)nb*40 + lane]; }
    a += va + vb;
  }
  if(e<s1 && act) a += X3[(size_t)esrc[e]*40 + lane];
  float v = act ? (a*norm[node] + b3[lane]) : -INFINITY;
  float mx = v;
  for(int off=32; off; off>>=1) mx = fmaxf(mx, __shfl_xor(mx, off, 64));
  float ex = act ? expf(v - mx) : 0.f;
  float sum = ex;
  for(int off=32; off; off>>=1) sum += __shfl_xor(sum, off, 64);
  if(act) out[(size_t)node*40 + lane] = v - mx - logf(sum);
}

// ---------------- GEMM (64x64 tile, fp32 accumulate, templated A dtype) ----------------

static __device__ __forceinline__ void loadA4(const float* p, float* o){
  float4 v = *(const float4*)p; o[0]=v.x; o[1]=v.y; o[2]=v.z; o[3]=v.w;
}
static __device__ __forceinline__ void loadA4(const unsigned short* p, float* o){
  uint2 v = *(const uint2*)p;
  o[0]=bflo(v.x); o[1]=bfhi(v.x); o[2]=bflo(v.y); o[3]=bfhi(v.y);
}

template<typename TA>
__global__ __launch_bounds__(256) void k_gemm(const TA* __restrict__ A, const float* __restrict__ B,
    const float* __restrict__ bias, const float* __restrict__ rownorm,
    float* __restrict__ C, int M, int K, int Nn){
  __shared__ float As[16][64];   // As[k][m]
  __shared__ float Bs[16][64];   // Bs[k][n]
  int ntile = (Nn+63)>>6;
  int bm = blockIdx.x / ntile, bn = blockIdx.x % ntile;
  int m0 = bm*64, n0 = bn*64;
  int tid = threadIdx.x;
  int tx = tid & 15, ty = tid >> 4;
  int arow = tid >> 2;        // 0..63
  int akk  = (tid & 3)*4;     // 0,4,8,12
  int bkk  = tid >> 4;        // 0..15
  int bj   = (tid & 15)*4;    // 0..60
  float acc[4][4] = {};
  for(int k0=0; k0<K; k0+=16){
    float av[4] = {0,0,0,0};
    if(m0+arow < M) loadA4(A + (size_t)(m0+arow)*K + k0 + akk, av);
    float bv[4] = {0,0,0,0};
    if(n0+bj+3 < Nn){
      float4 t = *(const float4*)(B + (size_t)(k0+bkk)*Nn + n0 + bj);
      bv[0]=t.x; bv[1]=t.y; bv[2]=t.z; bv[3]=t.w;
    }
    __syncthreads();   // previous tile's compute done
    As[akk+0][arow]=av[0]; As[akk+1][arow]=av[1]; As[akk+2][arow]=av[2]; As[akk+3][arow]=av[3];
    *(float4*)&Bs[bkk][bj] = make_float4(bv[0],bv[1],bv[2],bv[3]);
    __syncthreads();
    #pragma unroll
    for(int kk=0; kk<16; kk++){
      float4 a4 = *(const float4*)&As[kk][ty*4];
      float4 b4 = *(const float4*)&Bs[kk][tx*4];
      float aa[4]={a4.x,a4.y,a4.z,a4.w}, bb[4]={b4.x,b4.y,b4.z,b4.w};
      #pragma unroll
      for(int i=0;i<4;i++)
        #pragma unroll
        for(int j=0;j<4;j++)
          acc[i][j] += aa[i]*bb[j];
    }
  }
  float bias4[4] = {0,0,0,0};
  if(bias){
    #pragma unroll
    for(int j=0;j<4;j++){ int n=n0+tx*4+j; if(n<Nn) bias4[j]=bias[n]; }
  }
  #pragma unroll
  for(int i=0;i<4;i++){
    int m = m0 + ty*4 + i;
    if(m >= M) continue;
    float rn = rownorm ? rownorm[m] : 1.0f;
    #pragma unroll
    for(int j=0;j<4;j++){
      int n = n0 + tx*4 + j;
      if(n < Nn){
        float v = acc[i][j] + bias4[j];
        v *= rn;
        C[(size_t)m*Nn + n] = v;
      }
    }
  }
}

// ---------------- launch ----------------

extern "C" void kernel_launch(void* const* d_in, const int* in_sizes, int n_in,
                              void* d_out, int out_size, void* d_ws, size_t ws_size,
                              hipStream_t stream){
  const float* x   = (const float*)d_in[0];
  const int*   src = (const int*)d_in[1];
  const int*   dst = (const int*)d_in[2];
  const float* W1  = (const float*)d_in[3];
  const float* b1  = (const float*)d_in[4];
  const float* g1  = (const float*)d_in[5];
  const float* be1 = (const float*)d_in[6];
  const float* W2  = (const float*)d_in[7];
  const float* b2  = (const float*)d_in[8];
  const float* g2  = (const float*)d_in[9];
  const float* be2 = (const float*)d_in[10];
  const float* W3  = (const float*)d_in[11];
  const float* b3  = (const float*)d_in[12];
  float* out = (float*)d_out;
  const int N = NN;
  const int E = in_sizes[1];

  char* p = (char*)d_ws;
  size_t off = 0;
  auto alloc = [&](size_t bytes)->void*{
    void* r = p + off;
    off += (bytes + 511) & ~(size_t)511;
    return r;
  };
  // Total footprint ~219.2 MB — must stay safely under 256 MiB (round-0 crash
  // was a ~258 MiB layout overrunning d_ws).
  int*   cnt   = (int*)  alloc((size_t)N*4);
  int*   fill  = (int*)  alloc((size_t)N*4);
  float* sumsA = (float*)alloc(2048);
  float* sumsB = (float*)alloc(2048);
  size_t zero_bytes = off;                       // cnt|fill|sumsA|sumsB zeroed each call
  int*   rp    = (int*)  alloc((size_t)(N+1)*4);
  float* norm  = (float*)alloc((size_t)N*4);
  float* scshA = (float*)alloc(2048);
  float* scshB = (float*)alloc(2048);
  int*   esrc  = (int*)  alloc((size_t)E*4);
  unsigned short* Hbf = (unsigned short*)alloc((size_t)N*256*2);   // gather source, bf16
  unsigned short* Mbf = (unsigned short*)alloc((size_t)N*256*2);   // agg output, bf16
  float* bufZ  = (float*)alloc((size_t)N*256*4);                   // GEMM out, fp32; also X3 (N*40)
  (void)ws_size; (void)n_in; (void)out_size;

  hipMemsetAsync(d_ws, 0, zero_bytes, stream);

  int eb = (E+255)/256;
  k_hist   <<<eb,256,0,stream>>>(dst, cnt, E);
  k_norm   <<<(N+255)/256,256,0,stream>>>(cnt, norm, N);
  k_scan   <<<1,1024,0,stream>>>(cnt, rp, N);
  k_scatter<<<eb,256,0,stream>>>(src, dst, rp, fill, esrc, E);

  // layer 1: h0 = x*norm (bf16) -> agg(128) * norm -> @W1+b1 -> BN+ReLU (pre-mul norm)
  k_scale_x<<<(N*128+255)/256,256,0,stream>>>(x, norm, Hbf, N*128);
  k_agg128 <<<N,64,0,stream>>>(Hbf, rp, esrc, norm, Mbf);
  k_gemm<unsigned short><<<((N+63)/64)*4,256,0,stream>>>(Mbf, W1, b1, nullptr, bufZ, N, 128, 256);
  k_colstats<<<512,256,0,stream>>>(bufZ, sumsA, N);
  k_bnfin  <<<1,256,0,stream>>>(sumsA, g1, be1, scshA, N);
  k_bnrelu <<<(N*256+255)/256,256,0,stream>>>(bufZ, scshA, norm, Hbf, N*256);

  // layer 2: agg(256) * norm -> @W2+b2 -> BN+ReLU (no norm pre-mul; layer3 projects first)
  k_agg256 <<<N,64,0,stream>>>(Hbf, rp, esrc, norm, Mbf);
  k_gemm<unsigned short><<<((N+63)/64)*4,256,0,stream>>>(Mbf, W2, b2, nullptr, bufZ, N, 256, 256);
  k_colstats<<<512,256,0,stream>>>(bufZ, sumsB, N);
  k_bnfin  <<<1,256,0,stream>>>(sumsB, g2, be2, scshB, N);
  k_bnrelu <<<(N*256+255)/256,256,0,stream>>>(bufZ, scshB, nullptr, Hbf, N*256);

  // layer 3: X3 = (H2 @ W3) * norm[row] -> agg(40) * norm + b3 -> log_softmax
  k_gemm<unsigned short><<<((N+63)/64)*1,256,0,stream>>>(Hbf, W3, nullptr, norm, bufZ, N, 256, 40);
  k_agg40  <<<N,64,0,stream>>>(bufZ, rp, esrc, norm, b3, out);
}

// Round 3
// 1358.319 us; speedup vs baseline: 1.1282x; 1.1282x over previous
//
#include <hip/hip_runtime.h>
#include <cstdint>
#include <cstddef>

#define NN 100000
#define BN_EPS 1e-5f

typedef __attribute__((ext_vector_type(8))) short short8;
typedef __attribute__((ext_vector_type(4))) float f32x4;

static __device__ __forceinline__ float bflo(unsigned u){ return __uint_as_float(u<<16); }
static __device__ __forceinline__ float bfhi(unsigned u){ return __uint_as_float(u & 0xFFFF0000u); }
static __device__ __forceinline__ unsigned short f2bf(float f){
  unsigned u = __float_as_uint(f);
  u += 0x7FFFu + ((u>>16)&1u);   // round-to-nearest-even
  return (unsigned short)(u>>16);
}

// ---------------- graph prep ----------------

__global__ void k_hist(const int* __restrict__ dst, int* __restrict__ cnt, int E){
  int e = blockIdx.x*blockDim.x + threadIdx.x;
  if(e<E) atomicAdd(&cnt[dst[e]], 1);
}

__global__ void k_norm(const int* __restrict__ cnt, float* __restrict__ norm, int n){
  int i = blockIdx.x*blockDim.x + threadIdx.x;
  if(i<n) norm[i] = rsqrtf(fmaxf((float)cnt[i], 1.0f));
}

__global__ __launch_bounds__(1024) void k_scan(const int* __restrict__ cnt, int* __restrict__ rp, int n){
  __shared__ int sm[1024];
  int t = threadIdx.x;
  int chunk = (n + 1023)/1024;
  int lo = t*chunk, hi = min(lo+chunk, n);
  int s=0;
  for(int i=lo;i<hi;i++) s += cnt[i];
  sm[t]=s; __syncthreads();
  for(int off=1; off<1024; off<<=1){
    int v = (t>=off)? sm[t-off] : 0;
    __syncthreads();
    sm[t]+=v;
    __syncthreads();
  }
  int run = sm[t]-s;
  for(int i=lo;i<hi;i++){ rp[i]=run; run+=cnt[i]; }
  if(t==1023) rp[n]=sm[1023];
}

__global__ void k_scatter(const int* __restrict__ src, const int* __restrict__ dst,
                          const int* __restrict__ rp, int* __restrict__ fill,
                          int* __restrict__ esrc, int E){
  int e = blockIdx.x*blockDim.x + threadIdx.x;
  if(e<E){
    int d = dst[e];
    int pos = rp[d] + atomicAdd(&fill[d], 1);
    esrc[pos] = src[e];
  }
}

// ---------------- elementwise ----------------

__global__ void k_scale_x(const float* __restrict__ x, const float* __restrict__ norm,
                          unsigned short* __restrict__ H, int total){
  int i = blockIdx.x*blockDim.x + threadIdx.x;
  if(i<total) H[i] = f2bf(x[i] * norm[i>>7]);   // 128 feats/row
}

__global__ void k_bnrelu(const float* __restrict__ Z, const float* __restrict__ scsh,
                         const float* __restrict__ normPre, unsigned short* __restrict__ H, int total){
  int i = blockIdx.x*blockDim.x + threadIdx.x;
  if(i<total){
    int c = i & 255;
    float v = Z[i]*scsh[c] + scsh[256+c];
    v = fmaxf(v, 0.f);
    if(normPre) v *= normPre[i>>8];
    H[i] = f2bf(v);
  }
}

// weight prep: W (K x N fp32) -> Wt (N x K bf16)
__global__ void k_wprep(const float* __restrict__ W, unsigned short* __restrict__ Wt, int K, int N){
  int i = blockIdx.x*blockDim.x + threadIdx.x;
  if(i < K*N){
    int k = i / N, n = i - k*N;
    Wt[(size_t)n*K + k] = f2bf(W[i]);
  }
}

// ---------------- BN stats ----------------

__global__ __launch_bounds__(256) void k_colstats(const float* __restrict__ Z, float* __restrict__ sums, int M){
  int c = threadIdx.x;
  float s=0.f, s2=0.f;
  for(int r=blockIdx.x; r<M; r+=gridDim.x){
    float v = Z[(size_t)r*256 + c];
    s+=v; s2+=v*v;
  }
  atomicAdd(&sums[c], s);
  atomicAdd(&sums[256+c], s2);
}

__global__ void k_bnfin(const float* __restrict__ sums, const float* __restrict__ gamma,
                        const float* __restrict__ beta, float* __restrict__ scsh, int M){
  int c = threadIdx.x;
  float mean = sums[c]/(float)M;
  float var  = sums[256+c]/(float)M - mean*mean;
  float sc = gamma[c]*rsqrtf(var + BN_EPS);
  scsh[c] = sc;
  scsh[256+c] = beta[c] - mean*sc;
}

// ---------------- aggregation (wave per node, CSR) — bf16 out ----------------

__global__ __launch_bounds__(64) void k_agg128(const unsigned short* __restrict__ H,
    const int* __restrict__ rp, const int* __restrict__ esrc,
    const float* __restrict__ norm, unsigned short* __restrict__ out){
  int node = blockIdx.x, lane = threadIdx.x;
  int s0 = rp[node], s1 = rp[node+1];
  float a0=0.f, a1=0.f;
  int e=s0;
  for(; e+4<=s1; e+=4){
    int n0=esrc[e], n1=esrc[e+1], n2=esrc[e+2], n3=esrc[e+3];
    unsigned v0 = *(const unsigned*)(H + (size_t)n0*128 + lane*2);
    unsigned v1 = *(const unsigned*)(H + (size_t)n1*128 + lane*2);
    unsigned v2 = *(const unsigned*)(H + (size_t)n2*128 + lane*2);
    unsigned v3 = *(const unsigned*)(H + (size_t)n3*128 + lane*2);
    a0 += bflo(v0)+bflo(v1)+bflo(v2)+bflo(v3);
    a1 += bfhi(v0)+bfhi(v1)+bfhi(v2)+bfhi(v3);
  }
  for(; e<s1; e++){
    unsigned v = *(const unsigned*)(H + (size_t)esrc[e]*128 + lane*2);
    a0 += bflo(v); a1 += bfhi(v);
  }
  float nn = norm[node];
  unsigned pk = (unsigned)f2bf(a0*nn) | ((unsigned)f2bf(a1*nn) << 16);
  *(unsigned*)(out + (size_t)node*128 + lane*2) = pk;
}

__global__ __launch_bounds__(64) void k_agg256(const unsigned short* __restrict__ H,
    const int* __restrict__ rp, const int* __restrict__ esrc,
    const float* __restrict__ norm, unsigned short* __restrict__ out){
  int node = blockIdx.x, lane = threadIdx.x;
  int s0 = rp[node], s1 = rp[node+1];
  float a0=0.f,a1=0.f,a2=0.f,a3=0.f;
  int e=s0;
  for(; e+2<=s1; e+=2){
    int na=esrc[e], nb=esrc[e+1];
    uint2 va = *(const uint2*)(H + (size_t)na*256 + lane*4);
    uint2 vb = *(const uint2*)(H + (size_t)nb*256 + lane*4);
    a0 += bflo(va.x)+bflo(vb.x);
    a1 += bfhi(va.x)+bfhi(vb.x);
    a2 += bflo(va.y)+bflo(vb.y);
    a3 += bfhi(va.y)+bfhi(vb.y);
  }
  if(e<s1){
    uint2 v = *(const uint2*)(H + (size_t)esrc[e]*256 + lane*4);
    a0+=bflo(v.x); a1+=bfhi(v.x); a2+=bflo(v.y); a3+=bfhi(v.y);
  }
  float nn = norm[node];
  uint2 pk;
  pk.x = (unsigned)f2bf(a0*nn) | ((unsigned)f2bf(a1*nn) << 16);
  pk.y = (unsigned)f2bf(a2*nn) | ((unsigned)f2bf(a3*nn) << 16);
  *(uint2*)(out + (size_t)node*256 + lane*4) = pk;
}

// final aggregation over 40 bf16 features + bias + log_softmax, fused
__global__ __launch_bounds__(64) void k_agg40(const unsigned short* __restrict__ X3,
    const int* __restrict__ rp, const int* __restrict__ esrc,
    const float* __restrict__ norm, const float* __restrict__ b3,
    float* __restrict__ out){
  int node = blockIdx.x, lane = threadIdx.x;
  int s0 = rp[node], s1 = rp[node+1];
  bool act = lane < 40;
  float a = 0.f;
  int e = s0;
  for(; e+2<=s1; e+=2){
    int na=esrc[e], nb=esrc[e+1];
    float va=0.f, vb=0.f;
    if(act){ va = bflo(X3[(size_t)na*40 + lane]); vb = bflo(X3[(size_t)nb*40 + lane]); }
    a += va + vb;
  }
  if(e<s1 && act) a += bflo(X3[(size_t)esrc[e]*40 + lane]);
  float v = act ? (a*norm[node] + b3[lane]) : -INFINITY;
  float mx = v;
  for(int off=32; off; off>>=1) mx = fmaxf(mx, __shfl_xor(mx, off, 64));
  float ex = act ? expf(v - mx) : 0.f;
  float sum = ex;
  for(int off=32; off; off>>=1) sum += __shfl_xor(sum, off, 64);
  if(act) out[(size_t)node*40 + lane] = v - mx - logf(sum);
}

// ---------------- MFMA GEMM: C[M,N] = A[M,K](bf16) * Bt[N,K](bf16)^T + bias ----------------
// 128x128 tile, BK=64, global_load_lds staging, 16x16x32 bf16 MFMA.
// LDS layout: rows of 64 bf16 (128 B), 16 B chunks XOR-swizzled by (row&7)
// so quad-group ds_read_b128 spreads over all banks (2-way max).

__global__ __launch_bounds__(256) void k_mgemm(
    const unsigned short* __restrict__ A, const unsigned short* __restrict__ Bt,
    const float* __restrict__ bias, float* __restrict__ C, int M, int K, int Nn){
  __shared__ unsigned short As[128*64];
  __shared__ unsigned short Bs[128*64];
  int nt = Nn >> 7;
  int bm = blockIdx.x / nt, bn = blockIdx.x % nt;
  int m0 = bm*128, n0 = bn*128;
  int tid = threadIdx.x;
  int wave = tid >> 6, lane = tid & 63;
  int wm = (wave>>1)*64, wn = (wave&1)*64;
  int lrow = lane & 15, lq = lane >> 4;
  // staging: per inst, lane l -> LDS row (c*8 + (l>>3)), chunk (l&7); source chunk swizzled
  int srow = lane >> 3;                       // 0..7
  int sx = ((lane & 7) ^ srow) * 8;           // swizzled k-element offset within slab
  f32x4 acc[4][4] = {};
  for(int k0=0; k0<K; k0+=64){
    __syncthreads();                          // previous iter's LDS reads done
    #pragma unroll
    for(int c4=0;c4<4;c4++){
      int c = wave*4 + c4;
      int grow = c*8 + srow;
      const unsigned short* ga = A + (size_t)(m0+grow)*K + k0 + sx;
      __builtin_amdgcn_global_load_lds((const __attribute__((address_space(1))) void*)ga,
          (__attribute__((address_space(3))) void*)(As + (size_t)c*512), 16, 0, 0);
      const unsigned short* gb = Bt + (size_t)(n0+grow)*K + k0 + sx;
      __builtin_amdgcn_global_load_lds((const __attribute__((address_space(1))) void*)gb,
          (__attribute__((address_space(3))) void*)(Bs + (size_t)c*512), 16, 0, 0);
    }
    __syncthreads();                          // staging complete
    #pragma unroll
    for(int kk=0;kk<2;kk++){
      short8 af[4], bf[4];
      #pragma unroll
      for(int i=0;i<4;i++){
        int Ra = wm + i*16 + lrow;
        int ca = (kk*4 + lq) ^ (Ra & 7);
        af[i] = *(const short8*)(As + Ra*64 + ca*8);
        int Rb = wn + i*16 + lrow;
        int cb = (kk*4 + lq) ^ (Rb & 7);
        bf[i] = *(const short8*)(Bs + Rb*64 + cb*8);
      }
      #pragma unroll
      for(int i=0;i<4;i++)
        #pragma unroll
        for(int j=0;j<4;j++)
          acc[i][j] = __builtin_amdgcn_mfma_f32_16x16x32_bf16(af[i], bf[j], acc[i][j], 0, 0, 0);
    }
  }
  // epilogue: D col = lane&15, row = quad*4 + reg  [verified m89]
  #pragma unroll
  for(int j=0;j<4;j++){
    int col = n0 + wn + j*16 + lrow;
    float bj = bias ? bias[col] : 0.f;
    #pragma unroll
    for(int i=0;i<4;i++){
      #pragma unroll
      for(int r=0;r<4;r++){
        int row = m0 + wm + i*16 + lq*4 + r;
        if(row < M) C[(size_t)row*Nn + col] = acc[i][j][r] + bj;
      }
    }
  }
}

// ---------------- vector GEMM (layer 3 only: N=40), templated A/C dtype ----------------

static __device__ __forceinline__ void loadA4(const float* p, float* o){
  float4 v = *(const float4*)p; o[0]=v.x; o[1]=v.y; o[2]=v.z; o[3]=v.w;
}
static __device__ __forceinline__ void loadA4(const unsigned short* p, float* o){
  uint2 v = *(const uint2*)p;
  o[0]=bflo(v.x); o[1]=bfhi(v.x); o[2]=bflo(v.y); o[3]=bfhi(v.y);
}
static __device__ __forceinline__ void storeC(float* p, float v){ *p = v; }
static __device__ __forceinline__ void storeC(unsigned short* p, float v){ *p = f2bf(v); }

template<typename TA, typename TC>
__global__ __launch_bounds__(256) void k_gemm(const TA* __restrict__ A, const float* __restrict__ B,
    const float* __restrict__ bias, const float* __restrict__ rownorm,
    TC* __restrict__ C, int M, int K, int Nn){
  __shared__ float As[16][64];
  __shared__ float Bs[16][64];
  int ntile = (Nn+63)>>6;
  int bm = blockIdx.x / ntile, bn = blockIdx.x % ntile;
  int m0 = bm*64, n0 = bn*64;
  int tid = threadIdx.x;
  int tx = tid & 15, ty = tid >> 4;
  int arow = tid >> 2;
  int akk  = (tid & 3)*4;
  int bkk  = tid >> 4;
  int bj   = (tid & 15)*4;
  float acc[4][4] = {};
  for(int k0=0; k0<K; k0+=16){
    float av[4] = {0,0,0,0};
    if(m0+arow < M) loadA4(A + (size_t)(m0+arow)*K + k0 + akk, av);
    float bv[4] = {0,0,0,0};
    if(n0+bj+3 < Nn){
      float4 t = *(const float4*)(B + (size_t)(k0+bkk)*Nn + n0 + bj);
      bv[0]=t.x; bv[1]=t.y; bv[2]=t.z; bv[3]=t.w;
    }
    __syncthreads();
    As[akk+0][arow]=av[0]; As[akk+1][arow]=av[1]; As[akk+2][arow]=av[2]; As[akk+3][arow]=av[3];
    *(float4*)&Bs[bkk][bj] = make_float4(bv[0],bv[1],bv[2],bv[3]);
    __syncthreads();
    #pragma unroll
    for(int kk=0; kk<16; kk++){
      float4 a4 = *(const float4*)&As[kk][ty*4];
      float4 b4 = *(const float4*)&Bs[kk][tx*4];
      float aa[4]={a4.x,a4.y,a4.z,a4.w}, bb[4]={b4.x,b4.y,b4.z,b4.w};
      #pragma unroll
      for(int i=0;i<4;i++)
        #pragma unroll
        for(int j=0;j<4;j++)
          acc[i][j] += aa[i]*bb[j];
    }
  }
  float bias4[4] = {0,0,0,0};
  if(bias){
    #pragma unroll
    for(int j=0;j<4;j++){ int n=n0+tx*4+j; if(n<Nn) bias4[j]=bias[n]; }
  }
  #pragma unroll
  for(int i=0;i<4;i++){
    int m = m0 + ty*4 + i;
    if(m >= M) continue;
    float rn = rownorm ? rownorm[m] : 1.0f;
    #pragma unroll
    for(int j=0;j<4;j++){
      int n = n0 + tx*4 + j;
      if(n < Nn){
        float v = acc[i][j] + bias4[j];
        v *= rn;
        storeC(&C[(size_t)m*Nn + n], v);
      }
    }
  }
}

// ---------------- launch ----------------

extern "C" void kernel_launch(void* const* d_in, const int* in_sizes, int n_in,
                              void* d_out, int out_size, void* d_ws, size_t ws_size,
                              hipStream_t stream){
  const float* x   = (const float*)d_in[0];
  const int*   src = (const int*)d_in[1];
  const int*   dst = (const int*)d_in[2];
  const float* W1  = (const float*)d_in[3];
  const float* b1  = (const float*)d_in[4];
  const float* g1  = (const float*)d_in[5];
  const float* be1 = (const float*)d_in[6];
  const float* W2  = (const float*)d_in[7];
  const float* b2  = (const float*)d_in[8];
  const float* g2  = (const float*)d_in[9];
  const float* be2 = (const float*)d_in[10];
  const float* W3  = (const float*)d_in[11];
  const float* b3  = (const float*)d_in[12];
  float* out = (float*)d_out;
  const int N = NN;
  const int E = in_sizes[1];

  char* p = (char*)d_ws;
  size_t off = 0;
  auto alloc = [&](size_t bytes)->void*{
    void* r = p + off;
    off += (bytes + 511) & ~(size_t)511;
    return r;
  };
  // Footprint ~219.5 MB — stay safely under 256 MiB.
  int*   cnt   = (int*)  alloc((size_t)N*4);
  int*   fill  = (int*)  alloc((size_t)N*4);
  float* sumsA = (float*)alloc(2048);
  float* sumsB = (float*)alloc(2048);
  size_t zero_bytes = off;                       // cnt|fill|sumsA|sumsB zeroed each call
  int*   rp    = (int*)  alloc((size_t)(N+1)*4);
  float* norm  = (float*)alloc((size_t)N*4);
  float* scshA = (float*)alloc(2048);
  float* scshB = (float*)alloc(2048);
  unsigned short* Wt1 = (unsigned short*)alloc((size_t)256*128*2);
  unsigned short* Wt2 = (unsigned short*)alloc((size_t)256*256*2);
  int*   esrc  = (int*)  alloc((size_t)E*4);
  unsigned short* Hbf = (unsigned short*)alloc((size_t)N*256*2);   // gather source, bf16
  unsigned short* Mbf = (unsigned short*)alloc((size_t)N*256*2);   // agg output, bf16
  float* bufZ  = (float*)alloc((size_t)N*256*4);                   // GEMM out, fp32
  unsigned short* H3 = Mbf;                                        // layer-3 proj out (N*40 bf16), reuses Mbf
  (void)ws_size; (void)n_in; (void)out_size;

  hipMemsetAsync(d_ws, 0, zero_bytes, stream);

  int eb = (E+255)/256;
  k_hist   <<<eb,256,0,stream>>>(dst, cnt, E);
  k_norm   <<<(N+255)/256,256,0,stream>>>(cnt, norm, N);
  k_scan   <<<1,1024,0,stream>>>(cnt, rp, N);
  k_scatter<<<eb,256,0,stream>>>(src, dst, rp, fill, esrc, E);
  k_wprep  <<<(128*256+255)/256,256,0,stream>>>(W1, Wt1, 128, 256);
  k_wprep  <<<(256*256+255)/256,256,0,stream>>>(W2, Wt2, 256, 256);

  // layer 1: h0 = x*norm (bf16) -> agg(128)*norm -> MFMA @W1+b1 -> BN+ReLU (pre-mul norm)
  k_scale_x<<<(N*128+255)/256,256,0,stream>>>(x, norm, Hbf, N*128);
  k_agg128 <<<N,64,0,stream>>>(Hbf, rp, esrc, norm, Mbf);
  k_mgemm  <<<((N+127)/128)*2,256,0,stream>>>(Mbf, Wt1, b1, bufZ, N, 128, 256);
  k_colstats<<<512,256,0,stream>>>(bufZ, sumsA, N);
  k_bnfin  <<<1,256,0,stream>>>(sumsA, g1, be1, scshA, N);
  k_bnrelu <<<(N*256+255)/256,256,0,stream>>>(bufZ, scshA, norm, Hbf, N*256);

  // layer 2: agg(256)*norm -> MFMA @W2+b2 -> BN+ReLU
  k_agg256 <<<N,64,0,stream>>>(Hbf, rp, esrc, norm, Mbf);
  k_mgemm  <<<((N+127)/128)*2,256,0,stream>>>(Mbf, Wt2, b2, bufZ, N, 256, 256);
  k_colstats<<<512,256,0,stream>>>(bufZ, sumsB, N);
  k_bnfin  <<<1,256,0,stream>>>(sumsB, g2, be2, scshB, N);
  k_bnrelu <<<(N*256+255)/256,256,0,stream>>>(bufZ, scshB, nullptr, Hbf, N*256);

  // layer 3: X3 = (H2 @ W3)*norm[row] (bf16) -> agg(40)*norm + b3 -> log_softmax
  k_gemm<unsigned short, unsigned short><<<((N+63)/64)*1,256,0,stream>>>(Hbf, W3, nullptr, norm, H3, N, 256, 40);
  k_agg40  <<<N,64,0,stream>>>(H3, rp, esrc, norm, b3, out);
}

// Round 4
// 1264.533 us; speedup vs baseline: 1.2119x; 1.0742x over previous
//
#include <hip/hip_runtime.h>
#include <cstdint>
#include <cstddef>

#define NN 100000
#define BN_EPS 1e-5f

typedef __attribute__((ext_vector_type(8))) short short8;
typedef __attribute__((ext_vector_type(4))) float f32x4;

static __device__ __forceinline__ float bflo(unsigned u){ return __uint_as_float(u<<16); }
static __device__ __forceinline__ float bfhi(unsigned u){ return __uint_as_float(u & 0xFFFF0000u); }
static __device__ __forceinline__ unsigned short f2bf(float f){
  unsigned u = __float_as_uint(f);
  u += 0x7FFFu + ((u>>16)&1u);   // round-to-nearest-even
  return (unsigned short)(u>>16);
}

// ---------------- graph prep ----------------

__global__ void k_hist(const int* __restrict__ dst, int* __restrict__ cnt, int E){
  int e = blockIdx.x*blockDim.x + threadIdx.x;
  if(e<E) atomicAdd(&cnt[dst[e]], 1);
}

__global__ void k_norm(const int* __restrict__ cnt, float* __restrict__ norm, int n){
  int i = blockIdx.x*blockDim.x + threadIdx.x;
  if(i<n) norm[i] = rsqrtf(fmaxf((float)cnt[i], 1.0f));
}

// exclusive scan over PADDED counts (each node's range rounded up to multiple of 4)
__global__ __launch_bounds__(1024) void k_scan(const int* __restrict__ cnt, int* __restrict__ rp, int n){
  __shared__ int sm[1024];
  int t = threadIdx.x;
  int chunk = (n + 1023)/1024;
  int lo = t*chunk, hi = min(lo+chunk, n);
  int s=0;
  for(int i=lo;i<hi;i++) s += (cnt[i]+3)&~3;
  sm[t]=s; __syncthreads();
  for(int off=1; off<1024; off<<=1){
    int v = (t>=off)? sm[t-off] : 0;
    __syncthreads();
    sm[t]+=v;
    __syncthreads();
  }
  int run = sm[t]-s;
  for(int i=lo;i<hi;i++){ rp[i]=run; run+=(cnt[i]+3)&~3; }
  if(t==1023) rp[n]=sm[1023];
}

__global__ void k_scatter(const int* __restrict__ src, const int* __restrict__ dst,
                          const int* __restrict__ rp, int* __restrict__ fill,
                          int* __restrict__ esrc, int E){
  int e = blockIdx.x*blockDim.x + threadIdx.x;
  if(e<E){
    int d = dst[e];
    int pos = rp[d] + atomicAdd(&fill[d], 1);
    esrc[pos] = src[e];
  }
}

// fill pad slots with index NN (the dedicated zero row)
__global__ void k_pad(const int* __restrict__ cnt, const int* __restrict__ rp,
                      int* __restrict__ esrc, int n){
  int i = blockIdx.x*blockDim.x + threadIdx.x;
  if(i<n){
    int base = rp[i] + cnt[i], end = rp[i+1];
    for(int j=base;j<end;j++) esrc[j]=NN;
  }
}

// zero the pad rows of Hbf (row NN, 256 cols) and H3 (row NN, 40 cols)
__global__ void k_zeropad(unsigned short* __restrict__ Hbf, unsigned short* __restrict__ H3){
  int t = threadIdx.x;
  Hbf[(size_t)NN*256 + t] = 0;
  if(t<40) H3[(size_t)NN*40 + t] = 0;
}

// ---------------- elementwise ----------------

__global__ void k_scale_x(const float* __restrict__ x, const float* __restrict__ norm,
                          unsigned short* __restrict__ H, int total){
  int i = blockIdx.x*blockDim.x + threadIdx.x;
  if(i<total) H[i] = f2bf(x[i] * norm[i>>7]);   // 128 feats/row
}

// BN finalize fused: per-thread column stats from sums, then grid-stride rows
__global__ __launch_bounds__(256) void k_bnrelu(const float* __restrict__ Z,
    const float* __restrict__ sums, const float* __restrict__ gamma, const float* __restrict__ beta,
    const float* __restrict__ normPre, unsigned short* __restrict__ H, int M){
  int c = threadIdx.x;
  float mean = sums[c]/(float)M;
  float var  = sums[256+c]/(float)M - mean*mean;
  float sc = gamma[c]*rsqrtf(var + BN_EPS);
  float sh = beta[c] - mean*sc;
  for(int r=blockIdx.x; r<M; r+=gridDim.x){
    float v = fmaxf(Z[(size_t)r*256 + c]*sc + sh, 0.f);
    if(normPre) v *= normPre[r];
    H[(size_t)r*256 + c] = f2bf(v);
  }
}

// weight prep: W (K x N fp32) -> Wt (N x K bf16)
__global__ void k_wprep(const float* __restrict__ W, unsigned short* __restrict__ Wt, int K, int N){
  int i = blockIdx.x*blockDim.x + threadIdx.x;
  if(i < K*N){
    int k = i / N, n = i - k*N;
    Wt[(size_t)n*K + k] = f2bf(W[i]);
  }
}

// W3 (256 x 40 fp32) -> Wt3p (128 x 256 bf16), rows >= 40 zero
__global__ void k_wprep3(const float* __restrict__ W3, unsigned short* __restrict__ Wt){
  int i = blockIdx.x*blockDim.x + threadIdx.x;
  if(i < 128*256){
    int n = i >> 8, k = i & 255;
    Wt[i] = (n < 40) ? f2bf(W3[(size_t)k*40 + n]) : (unsigned short)0;
  }
}

// ---------------- BN stats ----------------

__global__ __launch_bounds__(256) void k_colstats(const float* __restrict__ Z, float* __restrict__ sums, int M){
  int c = threadIdx.x;
  float s=0.f, s2=0.f;
  for(int r=blockIdx.x; r<M; r+=gridDim.x){
    float v = Z[(size_t)r*256 + c];
    s+=v; s2+=v*v;
  }
  atomicAdd(&sums[c], s);
  atomicAdd(&sums[256+c], s2);
}

// ---------------- aggregation (wave per node, padded CSR) — bf16 out ----------------

__global__ __launch_bounds__(64) void k_agg128(const unsigned short* __restrict__ H,
    const int* __restrict__ rp, const int* __restrict__ esrc,
    const float* __restrict__ norm, unsigned short* __restrict__ out){
  int node = blockIdx.x, lane = threadIdx.x;
  int s0 = rp[node], s1 = rp[node+1];
  float a0=0.f, a1=0.f;
  if(s0<s1){
    int4 nx = *(const int4*)(esrc+s0);
    for(int e=s0; e<s1; e+=4){
      int4 cur = nx;
      int en = e+4;
      if(en<s1) nx = *(const int4*)(esrc+en);
      unsigned v0 = *(const unsigned*)(H + (size_t)cur.x*128 + lane*2);
      unsigned v1 = *(const unsigned*)(H + (size_t)cur.y*128 + lane*2);
      unsigned v2 = *(const unsigned*)(H + (size_t)cur.z*128 + lane*2);
      unsigned v3 = *(const unsigned*)(H + (size_t)cur.w*128 + lane*2);
      a0 += bflo(v0)+bflo(v1)+bflo(v2)+bflo(v3);
      a1 += bfhi(v0)+bfhi(v1)+bfhi(v2)+bfhi(v3);
    }
  }
  float nn = norm[node];
  unsigned pk = (unsigned)f2bf(a0*nn) | ((unsigned)f2bf(a1*nn) << 16);
  *(unsigned*)(out + (size_t)node*128 + lane*2) = pk;
}

__global__ __launch_bounds__(64) void k_agg256(const unsigned short* __restrict__ H,
    const int* __restrict__ rp, const int* __restrict__ esrc,
    const float* __restrict__ norm, unsigned short* __restrict__ out){
  int node = blockIdx.x, lane = threadIdx.x;
  int s0 = rp[node], s1 = rp[node+1];
  float a0=0.f,a1=0.f,a2=0.f,a3=0.f;
  if(s0<s1){
    int4 nx = *(const int4*)(esrc+s0);
    for(int e=s0; e<s1; e+=4){
      int4 cur = nx;
      int en = e+4;
      if(en<s1) nx = *(const int4*)(esrc+en);
      uint2 va = *(const uint2*)(H + (size_t)cur.x*256 + lane*4);
      uint2 vb = *(const uint2*)(H + (size_t)cur.y*256 + lane*4);
      uint2 vc = *(const uint2*)(H + (size_t)cur.z*256 + lane*4);
      uint2 vd = *(const uint2*)(H + (size_t)cur.w*256 + lane*4);
      a0 += bflo(va.x)+bflo(vb.x)+bflo(vc.x)+bflo(vd.x);
      a1 += bfhi(va.x)+bfhi(vb.x)+bfhi(vc.x)+bfhi(vd.x);
      a2 += bflo(va.y)+bflo(vb.y)+bflo(vc.y)+bflo(vd.y);
      a3 += bfhi(va.y)+bfhi(vb.y)+bfhi(vc.y)+bfhi(vd.y);
    }
  }
  float nn = norm[node];
  uint2 pk;
  pk.x = (unsigned)f2bf(a0*nn) | ((unsigned)f2bf(a1*nn) << 16);
  pk.y = (unsigned)f2bf(a2*nn) | ((unsigned)f2bf(a3*nn) << 16);
  *(uint2*)(out + (size_t)node*256 + lane*4) = pk;
}

// final aggregation over 40 bf16 features + bias + log_softmax, fused
__global__ __launch_bounds__(64) void k_agg40(const unsigned short* __restrict__ X3,
    const int* __restrict__ rp, const int* __restrict__ esrc,
    const float* __restrict__ norm, const float* __restrict__ b3,
    float* __restrict__ out){
  int node = blockIdx.x, lane = threadIdx.x;
  int s0 = rp[node], s1 = rp[node+1];
  bool act = lane < 40;
  float a = 0.f;
  if(s0<s1){
    int4 nx = *(const int4*)(esrc+s0);
    for(int e=s0; e<s1; e+=4){
      int4 cur = nx;
      int en = e+4;
      if(en<s1) nx = *(const int4*)(esrc+en);
      if(act){
        a += bflo(X3[(size_t)cur.x*40 + lane]);
        a += bflo(X3[(size_t)cur.y*40 + lane]);
        a += bflo(X3[(size_t)cur.z*40 + lane]);
        a += bflo(X3[(size_t)cur.w*40 + lane]);
      }
    }
  }
  float v = act ? (a*norm[node] + b3[lane]) : -INFINITY;
  float mx = v;
  for(int off=32; off; off>>=1) mx = fmaxf(mx, __shfl_xor(mx, off, 64));
  float ex = act ? expf(v - mx) : 0.f;
  float sum = ex;
  for(int off=32; off; off>>=1) sum += __shfl_xor(sum, off, 64);
  if(act) out[(size_t)node*40 + lane] = v - mx - logf(sum);
}

// ---------------- MFMA GEMM: C[M,N] = A[M,K](bf16) * Bt[N,K](bf16)^T + bias ----------------
// 128x128 tile, BK=64, global_load_lds staging, 16x16x32 bf16 MFMA.

__global__ __launch_bounds__(256) void k_mgemm(
    const unsigned short* __restrict__ A, const unsigned short* __restrict__ Bt,
    const float* __restrict__ bias, float* __restrict__ C, int M, int K, int Nn){
  __shared__ unsigned short As[128*64];
  __shared__ unsigned short Bs[128*64];
  int nt = Nn >> 7;
  int bm = blockIdx.x / nt, bn = blockIdx.x % nt;
  int m0 = bm*128, n0 = bn*128;
  int tid = threadIdx.x;
  int wave = tid >> 6, lane = tid & 63;
  int wm = (wave>>1)*64, wn = (wave&1)*64;
  int lrow = lane & 15, lq = lane >> 4;
  int srow = lane >> 3;
  int sx = ((lane & 7) ^ srow) * 8;
  f32x4 acc[4][4] = {};
  for(int k0=0; k0<K; k0+=64){
    __syncthreads();
    #pragma unroll
    for(int c4=0;c4<4;c4++){
      int c = wave*4 + c4;
      int grow = c*8 + srow;
      const unsigned short* ga = A + (size_t)(m0+grow)*K + k0 + sx;
      __builtin_amdgcn_global_load_lds((const __attribute__((address_space(1))) void*)ga,
          (__attribute__((address_space(3))) void*)(As + (size_t)c*512), 16, 0, 0);
      const unsigned short* gb = Bt + (size_t)(n0+grow)*K + k0 + sx;
      __builtin_amdgcn_global_load_lds((const __attribute__((address_space(1))) void*)gb,
          (__attribute__((address_space(3))) void*)(Bs + (size_t)c*512), 16, 0, 0);
    }
    __syncthreads();
    #pragma unroll
    for(int kk=0;kk<2;kk++){
      short8 af[4], bf[4];
      #pragma unroll
      for(int i=0;i<4;i++){
        int Ra = wm + i*16 + lrow;
        int ca = (kk*4 + lq) ^ (Ra & 7);
        af[i] = *(const short8*)(As + Ra*64 + ca*8);
        int Rb = wn + i*16 + lrow;
        int cb = (kk*4 + lq) ^ (Rb & 7);
        bf[i] = *(const short8*)(Bs + Rb*64 + cb*8);
      }
      #pragma unroll
      for(int i=0;i<4;i++)
        #pragma unroll
        for(int j=0;j<4;j++)
          acc[i][j] = __builtin_amdgcn_mfma_f32_16x16x32_bf16(af[i], bf[j], acc[i][j], 0, 0, 0);
    }
  }
  #pragma unroll
  for(int j=0;j<4;j++){
    int col = n0 + wn + j*16 + lrow;
    float bj = bias ? bias[col] : 0.f;
    #pragma unroll
    for(int i=0;i<4;i++){
      #pragma unroll
      for(int r=0;r<4;r++){
        int row = m0 + wm + i*16 + lq*4 + r;
        if(row < M) C[(size_t)row*Nn + col] = acc[i][j][r] + bj;
      }
    }
  }
}

// layer-3 variant: Nn=128 (cols>=40 are zero weights), writes bf16 * rownorm to H3 stride 40
__global__ __launch_bounds__(256) void k_mgemm3(
    const unsigned short* __restrict__ A, const unsigned short* __restrict__ Bt,
    const float* __restrict__ rownorm, unsigned short* __restrict__ H3, int M, int K){
  __shared__ unsigned short As[128*64];
  __shared__ unsigned short Bs[128*64];
  int m0 = blockIdx.x*128;
  int tid = threadIdx.x;
  int wave = tid >> 6, lane = tid & 63;
  int wm = (wave>>1)*64, wn = (wave&1)*64;
  int lrow = lane & 15, lq = lane >> 4;
  int srow = lane >> 3;
  int sx = ((lane & 7) ^ srow) * 8;
  f32x4 acc[4][4] = {};
  for(int k0=0; k0<K; k0+=64){
    __syncthreads();
    #pragma unroll
    for(int c4=0;c4<4;c4++){
      int c = wave*4 + c4;
      int grow = c*8 + srow;
      const unsigned short* ga = A + (size_t)(m0+grow)*K + k0 + sx;
      __builtin_amdgcn_global_load_lds((const __attribute__((address_space(1))) void*)ga,
          (__attribute__((address_space(3))) void*)(As + (size_t)c*512), 16, 0, 0);
      const unsigned short* gb = Bt + (size_t)grow*K + k0 + sx;
      __builtin_amdgcn_global_load_lds((const __attribute__((address_space(1))) void*)gb,
          (__attribute__((address_space(3))) void*)(Bs + (size_t)c*512), 16, 0, 0);
    }
    __syncthreads();
    #pragma unroll
    for(int kk=0;kk<2;kk++){
      short8 af[4], bf[4];
      #pragma unroll
      for(int i=0;i<4;i++){
        int Ra = wm + i*16 + lrow;
        int ca = (kk*4 + lq) ^ (Ra & 7);
        af[i] = *(const short8*)(As + Ra*64 + ca*8);
        int Rb = wn + i*16 + lrow;
        int cb = (kk*4 + lq) ^ (Rb & 7);
        bf[i] = *(const short8*)(Bs + Rb*64 + cb*8);
      }
      #pragma unroll
      for(int i=0;i<4;i++)
        #pragma unroll
        for(int j=0;j<4;j++)
          acc[i][j] = __builtin_amdgcn_mfma_f32_16x16x32_bf16(af[i], bf[j], acc[i][j], 0, 0, 0);
    }
  }
  #pragma unroll
  for(int j=0;j<4;j++){
    int col = wn + j*16 + lrow;
    if(col >= 40) continue;
    #pragma unroll
    for(int i=0;i<4;i++){
      #pragma unroll
      for(int r=0;r<4;r++){
        int row = m0 + wm + i*16 + lq*4 + r;
        if(row < M) H3[(size_t)row*40 + col] = f2bf(acc[i][j][r] * rownorm[row]);
      }
    }
  }
}

// ---------------- launch ----------------

extern "C" void kernel_launch(void* const* d_in, const int* in_sizes, int n_in,
                              void* d_out, int out_size, void* d_ws, size_t ws_size,
                              hipStream_t stream){
  const float* x   = (const float*)d_in[0];
  const int*   src = (const int*)d_in[1];
  const int*   dst = (const int*)d_in[2];
  const float* W1  = (const float*)d_in[3];
  const float* b1  = (const float*)d_in[4];
  const float* g1  = (const float*)d_in[5];
  const float* be1 = (const float*)d_in[6];
  const float* W2  = (const float*)d_in[7];
  const float* b2  = (const float*)d_in[8];
  const float* g2  = (const float*)d_in[9];
  const float* be2 = (const float*)d_in[10];
  const float* W3  = (const float*)d_in[11];
  const float* b3  = (const float*)d_in[12];
  float* out = (float*)d_out;
  const int N = NN;
  const int E = in_sizes[1];

  char* p = (char*)d_ws;
  size_t off = 0;
  auto alloc = [&](size_t bytes)->void*{
    void* r = p + off;
    off += (bytes + 511) & ~(size_t)511;
    return r;
  };
  // Footprint ~229 MB — stay safely under 256 MiB.
  int*   cnt   = (int*)  alloc((size_t)N*4);
  int*   fill  = (int*)  alloc((size_t)N*4);
  float* sumsA = (float*)alloc(2048);
  float* sumsB = (float*)alloc(2048);
  size_t zero_bytes = off;                       // cnt|fill|sumsA|sumsB zeroed each call
  int*   rp    = (int*)  alloc((size_t)(N+1)*4);
  float* norm  = (float*)alloc((size_t)N*4);
  unsigned short* Wt1 = (unsigned short*)alloc((size_t)256*128*2);
  unsigned short* Wt2 = (unsigned short*)alloc((size_t)256*256*2);
  unsigned short* Wt3 = (unsigned short*)alloc((size_t)128*256*2);
  int*   esrc  = (int*)  alloc((size_t)(E + 3*N + 8)*4);           // padded CSR
  unsigned short* Hbf = (unsigned short*)alloc((size_t)(N+1)*256*2); // gather source + zero row
  unsigned short* Mbf = (unsigned short*)alloc((size_t)N*256*2);     // agg output
  unsigned short* H3  = (unsigned short*)alloc((size_t)(N+1)*40*2);  // layer-3 proj + zero row
  float* bufZ  = (float*)alloc((size_t)N*256*4);                     // GEMM out, fp32
  (void)ws_size; (void)n_in; (void)out_size;

  hipMemsetAsync(d_ws, 0, zero_bytes, stream);

  int eb = (E+255)/256;
  k_hist   <<<eb,256,0,stream>>>(dst, cnt, E);
  k_norm   <<<(N+255)/256,256,0,stream>>>(cnt, norm, N);
  k_scan   <<<1,1024,0,stream>>>(cnt, rp, N);
  k_scatter<<<eb,256,0,stream>>>(src, dst, rp, fill, esrc, E);
  k_pad    <<<(N+255)/256,256,0,stream>>>(cnt, rp, esrc, N);
  k_zeropad<<<1,256,0,stream>>>(Hbf, H3);
  k_wprep  <<<(128*256+255)/256,256,0,stream>>>(W1, Wt1, 128, 256);
  k_wprep  <<<(256*256+255)/256,256,0,stream>>>(W2, Wt2, 256, 256);
  k_wprep3 <<<(128*256+255)/256,256,0,stream>>>(W3, Wt3);

  // layer 1
  k_scale_x<<<(N*128+255)/256,256,0,stream>>>(x, norm, Hbf, N*128);
  k_agg128 <<<N,64,0,stream>>>(Hbf, rp, esrc, norm, Mbf);
  k_mgemm  <<<((N+127)/128)*2,256,0,stream>>>(Mbf, Wt1, b1, bufZ, N, 128, 256);
  k_colstats<<<512,256,0,stream>>>(bufZ, sumsA, N);
  k_bnrelu <<<2048,256,0,stream>>>(bufZ, sumsA, g1, be1, norm, Hbf, N);

  // layer 2
  k_agg256 <<<N,64,0,stream>>>(Hbf, rp, esrc, norm, Mbf);
  k_mgemm  <<<((N+127)/128)*2,256,0,stream>>>(Mbf, Wt2, b2, bufZ, N, 256, 256);
  k_colstats<<<512,256,0,stream>>>(bufZ, sumsB, N);
  k_bnrelu <<<2048,256,0,stream>>>(bufZ, sumsB, g2, be2, nullptr, Hbf, N);

  // layer 3
  k_mgemm3 <<<(N+127)/128,256,0,stream>>>(Hbf, Wt3, norm, H3, N, 256);
  k_agg40  <<<N,64,0,stream>>>(H3, rp, esrc, norm, b3, out);
}